// Round 4
// baseline (9874.879 us; speedup 1.0000x reference)
//
#include <hip/hip_runtime.h>
#include <stdint.h>
#include <stddef.h>

#define S_LEN 512
#define BATCH 256
#define NIN   64
#define HD    512
#define G4    2048   // 4*H
#define RING_D 32    // ring depth (pow2)
#define BT    64     // batch rows per WG

typedef _Float16 f16;
typedef _Float16 f16x8 __attribute__((ext_vector_type(8)));
typedef float    f32x4 __attribute__((ext_vector_type(4)));
typedef uint32_t u32x4 __attribute__((ext_vector_type(4)));
typedef uint64_t u64x2 __attribute__((ext_vector_type(2)));

// ============================ prep kernels ============================
__global__ void k_f32_to_f16(const float* __restrict__ src, f16* __restrict__ dst, int n) {
  int i = blockIdx.x * 256 + threadIdx.x;
  if (i < n) dst[i] = (f16)src[i];
}

// x [B,S,I] fp32 -> xin [(s*256+b)*64+i] fp16
__global__ void k_x_transpose(const float* __restrict__ x, f16* __restrict__ xin) {
  int idx = blockIdx.x * 256 + threadIdx.x;
  int i  = idx & 63;
  int sb = idx >> 6;
  int b  = sb & 255;
  int s  = sb >> 8;
  xin[idx] = (f16)x[((size_t)b * S_LEN + s) * NIN + i];
}

__global__ void k_zero_i32(uint32_t* p, int n) {
  int i = blockIdx.x * 256 + threadIdx.x;
  if (i < n) p[i] = 0u;
}

// ====================== fused 3-layer systolic LSTM — overlapped phases ======================
// 192 WGs x 512 threads, 1 WG/CU (LDS 160 KiB). blockIdx = l*64 + bi*16 + gi.
// Wave role: g = wave>>1 (gate), kh = wave&1 (0: Whh/critical-chain, 1: Wih/off-chain).
//
// R3 lesson: step is LATENCY-exposed at 2 waves/SIMD (halving LDS traffic changed nothing).
// Fix: 3-phase schedule overlapping the off-chain Wih work with the serial Whh chain:
//   PhA: kh0 {poll siblings + fnext; stage own-h(t-1) -> lh}   [VMEM]
//        kh1 {MFMA lg1(t) = lhp @ Wih^T -> store into lgsum}   [MFMA/LDS]  (lhp staged last iter)
//   BAR1
//   PhB: kh0 {MFMA lg0(t) = lh @ Whh^T; lgsum[pos] += acc}     [MFMA/LDS]
//        kh1 {poll fprev>=t+2; stage prev-h(t+1) -> lhp}       [VMEM]      (skip at t=S-1!)
//   BAR2
//   PhC: all  {ew: gates = lgsum + bias; c,h update (__expf); h -> ring}
//   BAR3; tid0 bumps flag.
// LDS: lh 64K + lhp 64K + lgsum 32K = 160K exactly; NO aliasing (fewer hazards, 3 barriers).
// Sync protocol identical to proven R2/R3 (monotone flags; relaxed agent ring; flag only
// after __syncthreads drains data-store vmcnt). New: fprev>=t+2 (guarded t<S-1 — polling
// t+2=S+1 would deadlock), fnext>=t-28 (provable bound t-32, margin 4).
__global__ __launch_bounds__(512, 2) void k_fused(
    const f16* __restrict__ whh,     // [3][2048][512] fp16
    const f16* __restrict__ wih,     // [3] slabs of G4*HD; layer0 packed [2048][64]
    const float* __restrict__ b0,
    const float* __restrict__ b1,
    const float* __restrict__ b2,
    const f16* __restrict__ xin,     // [512*256][64] fp16
    f16* __restrict__ ring,          // [3][RING_D][256][512] fp16
    int* __restrict__ flags,         // [3][4][16]
    f16* __restrict__ hlast) {       // [256][512] fp16
  const int tid  = threadIdx.x;
  const int lane = tid & 63;
  const int wave = tid >> 6;          // 0..7
  const int l    = blockIdx.x >> 6;   // 0..2
  const int bi   = (blockIdx.x >> 4) & 3;
  const int gi   = blockIdx.x & 15;
  const int ln   = lane & 15;
  const int quad = lane >> 4;
  const int g    = wave >> 1;         // gate 0..3
  const int kh   = wave & 1;          // 0: Whh chain, 1: Wih off-chain
  const int gt   = (wave >> 1) * 64 + lane;  // 0..255 within kh-group

  __shared__ __align__(16) char smem[163840];
  char*  lh_b  = smem;                   // 64 KiB own h_{t-1} tile (64 rows x 1024B)
  char*  lhp_b = smem + 65536;           // 64 KiB prev h_t tile / x_t tile
  float* lgsum = (float*)(smem + 131072);// 32 KiB merged gate accum [64][128]

  auto swz = [](int row, int boff) { return row * 1024 + (boff ^ ((row & 7) << 4)); };
  auto lgpos = [](int row, int col) { return row * 128 + (col ^ (((row >> 2) & 7) << 2)); };

  const f16* whh_l = whh + (size_t)l * G4 * HD;
  const f16* wih_l = wih + (size_t)l * G4 * HD;
  const float* bias_l = (l == 0) ? b0 : (l == 1 ? b1 : b2);

  // --- weight fragments -> registers (kh0: Whh; kh1: Wih); asm launder pins them ---
  f16x8 wf[16][2];
  if (kh == 0 || l > 0) {
    const f16* W = kh ? wih_l : whh_l;
#pragma unroll
    for (int nb = 0; nb < 2; nb++) {
      const int r = g * 512 + gi * 32 + nb * 16 + ln;   // row in [2048, 512]
#pragma unroll
      for (int ks = 0; ks < 16; ks++) {
        u32x4 tmp = *(const u32x4*)(W + (size_t)r * HD + ks * 32 + quad * 8);
        asm volatile("" : "+v"(tmp));
        wf[ks][nb] = __builtin_bit_cast(f16x8, tmp);
      }
    }
  } else {  // l==0, kh==1: Wih1 is [2048][64]
#pragma unroll
    for (int nb = 0; nb < 2; nb++) {
      const int r = g * 512 + gi * 32 + nb * 16 + ln;
#pragma unroll
      for (int ks = 0; ks < 2; ks++) {
        u32x4 tmp = *(const u32x4*)(wih_l + (size_t)r * NIN + ks * 32 + quad * 8);
        asm volatile("" : "+v"(tmp));
        wf[ks][nb] = __builtin_bit_cast(f16x8, tmp);
      }
    }
  }

  // --- per-thread elementwise state: 4 rows x 1 h-col ---
  const int brow = tid >> 5;
  const int hl_  = tid & 31;
  float cv[4] = {0.f, 0.f, 0.f, 0.f};
  const float bv0 = bias_l[0 * HD + gi * 32 + hl_];
  const float bv1 = bias_l[1 * HD + gi * 32 + hl_];
  const float bv2 = bias_l[2 * HD + gi * 32 + hl_];
  const float bv3 = bias_l[3 * HD + gi * 32 + hl_];

  int* fown = flags + l * 64 + bi * 16;
  int* myflag = fown + gi;
  const int* fprev = (l > 0) ? (flags + (l - 1) * 64 + bi * 16) : fown;
  const int* fnext = (l < 2) ? (flags + (l + 1) * 64 + bi * 16) : fown;

  // ---------------- prologue: lhp <- h^prev_0 (prev ring slot 1) or x_0 ----------------
  if (l > 0) {
    int v = __hip_atomic_load(fprev + ln, __ATOMIC_RELAXED, __HIP_MEMORY_SCOPE_AGENT);
    while (!__all(v >= 1)) {
      __builtin_amdgcn_s_sleep(1);
      v = __hip_atomic_load(fprev + ln, __ATOMIC_RELAXED, __HIP_MEMORY_SCOPE_AGENT);
    }
    asm volatile("" ::: "memory");
    const uint64_t* hp = (const uint64_t*)(ring
        + ((size_t)(l - 1) * RING_D + 1) * (BATCH * HD) + (size_t)(bi * BT) * HD);
    uint64_t p0[8], p1[8];
#pragma unroll
    for (int j = 0; j < 8; j++) {
      p0[j] = __hip_atomic_load(hp + j * 1024 + tid * 2,     __ATOMIC_RELAXED, __HIP_MEMORY_SCOPE_AGENT);
      p1[j] = __hip_atomic_load(hp + j * 1024 + tid * 2 + 1, __ATOMIC_RELAXED, __HIP_MEMORY_SCOPE_AGENT);
    }
#pragma unroll
    for (int j = 0; j < 8; j++) {
      const int e = j * 1024 + tid * 2, row = e >> 7, c8 = e & 127;
      u64x2 p; p[0] = p0[j]; p[1] = p1[j];
      *(u64x2*)(lhp_b + swz(row, c8 * 8)) = p;
    }
  } else {
    const int xr = tid >> 3, xc = tid & 7;    // 512 chunks of 16B over 64 rows
    u32x4 xv = *(const u32x4*)(xin + ((size_t)(bi * BT + xr)) * NIN + xc * 8);
    *(u32x4*)(lhp_b + swz(xr, xc * 16)) = xv;
  }
  __syncthreads();

  for (int t = 0; t < S_LEN; t++) {
    const bool lastT = (t == S_LEN - 1);

    // =============== Phase A ===============
    if (kh == 0) {
      // poll own-line (need t); quad2 carries the fnext back-pressure check
      {
        const int* fp = fown; int need = t;
        if (quad == 2 && l < 2) { fp = fnext; need = t - 28; }
        int v = __hip_atomic_load(fp + ln, __ATOMIC_RELAXED, __HIP_MEMORY_SCOPE_AGENT);
        while (!__all(v >= need)) {
          __builtin_amdgcn_s_sleep(1);
          v = __hip_atomic_load(fp + ln, __ATOMIC_RELAXED, __HIP_MEMORY_SCOPE_AGENT);
        }
      }
      asm volatile("" ::: "memory");
      // stage own h_{t-1} (slot t%D) -> lh : 256 threads x 16 b128 (2 half-batches)
      const uint64_t* hown = (const uint64_t*)(ring
          + ((size_t)l * RING_D + (t & (RING_D - 1))) * (BATCH * HD)
          + (size_t)(bi * BT) * HD);
#pragma unroll
      for (int b = 0; b < 2; b++) {
        uint64_t q0[8], q1[8];
#pragma unroll
        for (int j = 0; j < 8; j++) {
          const int e = (b * 8 + j) * 512 + gt * 2;
          q0[j] = __hip_atomic_load(hown + e,     __ATOMIC_RELAXED, __HIP_MEMORY_SCOPE_AGENT);
          q1[j] = __hip_atomic_load(hown + e + 1, __ATOMIC_RELAXED, __HIP_MEMORY_SCOPE_AGENT);
        }
#pragma unroll
        for (int j = 0; j < 8; j++) {
          const int e = (b * 8 + j) * 512 + gt * 2, row = e >> 7, c8 = e & 127;
          u64x2 p; p[0] = q0[j]; p[1] = q1[j];
          *(u64x2*)(lh_b + swz(row, c8 * 8)) = p;
        }
      }
    } else {
      // kh1: lg1(t) = lhp @ Wih^T  (lhp staged last iteration; BAR2/BAR3 fenced)
      f32x4 acc[4][2] = {};
      const int nks = (l == 0) ? 2 : 16;
      for (int ks = 0; ks < nks; ks++) {
        f16x8 af[4];
#pragma unroll
        for (int mi = 0; mi < 4; mi++)
          af[mi] = *(const f16x8*)(lhp_b + swz(mi * 16 + ln, ks * 64 + quad * 16));
#pragma unroll
        for (int mi = 0; mi < 4; mi++)
#pragma unroll
          for (int nb = 0; nb < 2; nb++)
            acc[mi][nb] = __builtin_amdgcn_mfma_f32_16x16x32_f16(af[mi], wf[ks][nb], acc[mi][nb], 0, 0, 0);
      }
#pragma unroll
      for (int mi = 0; mi < 4; mi++)
#pragma unroll
        for (int nb = 0; nb < 2; nb++)
#pragma unroll
          for (int rr = 0; rr < 4; rr++) {
            const int row = mi * 16 + quad * 4 + rr;
            const int col = g * 32 + nb * 16 + ln;
            lgsum[lgpos(row, col)] = acc[mi][nb][rr];   // plain store; kh0 adds in PhB
          }
    }
    __syncthreads();   // BAR1: lh staged, lg1 written, lhp fully read

    // =============== Phase B ===============
    if (kh == 0) {
      f32x4 acc[4][2] = {};
#pragma unroll
      for (int ks = 0; ks < 16; ks++) {
        f16x8 af[4];
#pragma unroll
        for (int mi = 0; mi < 4; mi++)
          af[mi] = *(const f16x8*)(lh_b + swz(mi * 16 + ln, ks * 64 + quad * 16));
#pragma unroll
        for (int mi = 0; mi < 4; mi++)
#pragma unroll
          for (int nb = 0; nb < 2; nb++)
            acc[mi][nb] = __builtin_amdgcn_mfma_f32_16x16x32_f16(af[mi], wf[ks][nb], acc[mi][nb], 0, 0, 0);
      }
#pragma unroll
      for (int mi = 0; mi < 4; mi++)
#pragma unroll
        for (int nb = 0; nb < 2; nb++)
#pragma unroll
          for (int rr = 0; rr < 4; rr++) {
            const int row = mi * 16 + quad * 4 + rr;
            const int col = g * 32 + nb * 16 + ln;
            lgsum[lgpos(row, col)] += acc[mi][nb][rr];
          }
    } else if (!lastT) {
      if (l > 0) {
        // poll fprev >= t+2, then stage prev h_{t+1} (slot (t+2)%D) -> lhp
        int v = __hip_atomic_load(fprev + ln, __ATOMIC_RELAXED, __HIP_MEMORY_SCOPE_AGENT);
        while (!__all(v >= t + 2)) {
          __builtin_amdgcn_s_sleep(1);
          v = __hip_atomic_load(fprev + ln, __ATOMIC_RELAXED, __HIP_MEMORY_SCOPE_AGENT);
        }
        asm volatile("" ::: "memory");
        const uint64_t* hp = (const uint64_t*)(ring
            + ((size_t)(l - 1) * RING_D + ((t + 2) & (RING_D - 1))) * (BATCH * HD)
            + (size_t)(bi * BT) * HD);
#pragma unroll
        for (int b = 0; b < 2; b++) {
          uint64_t q0[8], q1[8];
#pragma unroll
          for (int j = 0; j < 8; j++) {
            const int e = (b * 8 + j) * 512 + gt * 2;
            q0[j] = __hip_atomic_load(hp + e,     __ATOMIC_RELAXED, __HIP_MEMORY_SCOPE_AGENT);
            q1[j] = __hip_atomic_load(hp + e + 1, __ATOMIC_RELAXED, __HIP_MEMORY_SCOPE_AGENT);
          }
#pragma unroll
          for (int j = 0; j < 8; j++) {
            const int e = (b * 8 + j) * 512 + gt * 2, row = e >> 7, c8 = e & 127;
            u64x2 p; p[0] = q0[j]; p[1] = q1[j];
            *(u64x2*)(lhp_b + swz(row, c8 * 8)) = p;
          }
        }
      } else {
        // x_{t+1} tile (8 KiB): 256 threads x 2 b128 chunks
#pragma unroll
        for (int j = 0; j < 2; j++) {
          const int cid = j * 256 + gt, xr = cid >> 3, xc = cid & 7;
          u32x4 xv = *(const u32x4*)(xin + ((size_t)((t + 1) * 256 + bi * BT + xr)) * NIN + xc * 8);
          *(u32x4*)(lhp_b + swz(xr, xc * 16)) = xv;
        }
      }
    }
    __syncthreads();   // BAR2: lgsum complete, lhp restaged

    // =============== Phase C: elementwise ===============
    f16* hout = ring + ((size_t)l * RING_D + ((t + 1) & (RING_D - 1))) * (BATCH * HD);
#pragma unroll
    for (int s = 0; s < 4; s++) {
      const int row = brow + s * 16;
      float g0 = lgsum[lgpos(row, 0  + hl_)] + bv0;
      float g1 = lgsum[lgpos(row, 32 + hl_)] + bv1;
      float g2 = lgsum[lgpos(row, 64 + hl_)] + bv2;
      float g3 = lgsum[lgpos(row, 96 + hl_)] + bv3;
      const float igt = 1.f / (1.f + __expf(-g0));
      const float fgt = 1.f / (1.f + __expf(-g1));
      const float ggt = g2 > 0.f ? g2 : (__expf(g2) - 1.f);
      const float ogt = 1.f / (1.f + __expf(-g3));
      cv[s] = fgt * cv[s] + igt * ggt;
      const float hv = ogt * (cv[s] > 0.f ? cv[s] : (__expf(cv[s]) - 1.f));
      f16 hv16 = (f16)hv;
      unsigned short us;
      __builtin_memcpy(&us, &hv16, 2);
      const size_t col = (size_t)(bi * BT + row) * HD + gi * 32 + hl_;
      __hip_atomic_store((unsigned short*)(hout + col), us,
                         __ATOMIC_RELAXED, __HIP_MEMORY_SCOPE_AGENT);
      if (l == 2 && t == S_LEN - 1) hlast[col] = hv16;
    }
    __syncthreads();   // BAR3: drains every wave's vmcnt -> all h stores at coherence point
    if (tid == 0)
      __hip_atomic_store(myflag, t + 1, __ATOMIC_RELAXED, __HIP_MEMORY_SCOPE_AGENT);
  }
}

// ====================== final FC: y[b] = h_last[b,:] . fc_w + fc_b ======================
__global__ __launch_bounds__(64) void k_fc(const f16* __restrict__ hlast,
                                           const float* __restrict__ fcw,
                                           const float* __restrict__ fcb,
                                           float* __restrict__ out) {
  const int b = blockIdx.x, lane = threadIdx.x;
  const f16* hp = hlast + (size_t)b * HD + lane * 8;
  float s = 0.f;
#pragma unroll
  for (int j = 0; j < 8; j++) s += (float)hp[j] * fcw[lane * 8 + j];
  for (int off = 32; off; off >>= 1) s += __shfl_down(s, off);
  if (lane == 0) out[b] = s + fcb[0];
}

// ============================ host ============================
extern "C" void kernel_launch(void* const* d_in, const int* in_sizes, int n_in,
                              void* d_out, int out_size, void* d_ws, size_t ws_size,
                              hipStream_t stream) {
  (void)in_sizes; (void)n_in; (void)out_size; (void)ws_size;
  const float* x      = (const float*)d_in[0];
  const float* wih[3] = {(const float*)d_in[1], (const float*)d_in[4], (const float*)d_in[7]};
  const float* whh[3] = {(const float*)d_in[2], (const float*)d_in[5], (const float*)d_in[8]};
  const float* bia[3] = {(const float*)d_in[3], (const float*)d_in[6], (const float*)d_in[9]};
  const float* fcw = (const float*)d_in[10];
  const float* fcb = (const float*)d_in[11];
  float* out = (float*)d_out;

  char* ws = (char*)d_ws;
  size_t off = 0;
  auto alloc = [&](size_t bytes) -> char* {
    off = (off + 255) & ~(size_t)255;
    char* p = ws + off;
    off += bytes;
    return p;
  };

  f16* xin   = (f16*)alloc((size_t)S_LEN * BATCH * NIN * 2);
  f16* wih16 = (f16*)alloc((size_t)3 * G4 * HD * 2);
  f16* whh16 = (f16*)alloc((size_t)3 * G4 * HD * 2);
  f16* ring  = (f16*)alloc((size_t)3 * RING_D * BATCH * HD * 2);
  int* flags = (int*)alloc(256 * 4);
  f16* hlast = (f16*)alloc((size_t)BATCH * HD * 2);

  // ---- prep ----
  {
    int n = S_LEN * BATCH * NIN;
    k_x_transpose<<<dim3(n / 256), dim3(256), 0, stream>>>(x, xin);
  }
  k_f32_to_f16<<<dim3((G4 * NIN + 255) / 256), dim3(256), 0, stream>>>(wih[0], wih16, G4 * NIN);
  k_f32_to_f16<<<dim3((G4 * HD + 255) / 256), dim3(256), 0, stream>>>(wih[1], wih16 + (size_t)G4 * HD, G4 * HD);
  k_f32_to_f16<<<dim3((G4 * HD + 255) / 256), dim3(256), 0, stream>>>(wih[2], wih16 + (size_t)2 * G4 * HD, G4 * HD);
  for (int l = 0; l < 3; l++)
    k_f32_to_f16<<<dim3((G4 * HD + 255) / 256), dim3(256), 0, stream>>>(whh[l], whh16 + (size_t)l * G4 * HD, G4 * HD);
  // zero ring slot 0 of each layer (h_{-1}=0) + flags
  for (int l = 0; l < 3; l++)
    k_zero_i32<<<dim3(BATCH * HD / 2 / 256), dim3(256), 0, stream>>>(
        (uint32_t*)(ring + (size_t)l * RING_D * BATCH * HD), BATCH * HD / 2);
  k_zero_i32<<<dim3(1), dim3(256), 0, stream>>>((uint32_t*)flags, 192);

  // ---- single fused systolic launch (192 WGs, 1/CU, overlapped phases) ----
  k_fused<<<dim3(192), dim3(512), 0, stream>>>(whh16, wih16, bia[0], bia[1], bia[2],
                                               xin, ring, flags, hlast);

  // ---- final FC ----
  k_fc<<<dim3(BATCH), dim3(64), 0, stream>>>(hlast, fcw, fcb, out);
}

// Round 5
// 7720.620 us; speedup vs baseline: 1.2790x; 1.2790x over previous
//
#include <hip/hip_runtime.h>
#include <stdint.h>
#include <stddef.h>

#define S_LEN 512
#define BATCH 256
#define NIN   64
#define HD    512
#define G4    2048   // 4*H
#define RING_D 32    // ring depth (pow2)
#define BT    64     // batch rows per WG

typedef _Float16 f16;
typedef _Float16 f16x8 __attribute__((ext_vector_type(8)));
typedef float    f32x4 __attribute__((ext_vector_type(4)));
typedef uint32_t u32x4 __attribute__((ext_vector_type(4)));

typedef __attribute__((address_space(3))) void lds_as;
typedef const __attribute__((address_space(1))) void glb_as;

// async global->LDS, 16B/lane, wave-uniform LDS base + lane*16; aux=17 = SC0|SC1
// (device-coherent MALL path, same coherence class as the proven relaxed agent atomics)
static __device__ __forceinline__ void gll16(const void* g, void* l) {
  __builtin_amdgcn_global_load_lds((glb_as*)g, (lds_as*)l, 16, 0, 17);
}

// ============================ prep kernels ============================
__global__ void k_f32_to_f16(const float* __restrict__ src, f16* __restrict__ dst, int n) {
  int i = blockIdx.x * 256 + threadIdx.x;
  if (i < n) dst[i] = (f16)src[i];
}

// x [B,S,I] fp32 -> xin [(s*256+b)*64+i] fp16
__global__ void k_x_transpose(const float* __restrict__ x, f16* __restrict__ xin) {
  int idx = blockIdx.x * 256 + threadIdx.x;
  int i  = idx & 63;
  int sb = idx >> 6;
  int b  = sb & 255;
  int s  = sb >> 8;
  xin[idx] = (f16)x[((size_t)b * S_LEN + s) * NIN + i];
}

__global__ void k_zero_i32(uint32_t* p, int n) {
  int i = blockIdx.x * 256 + threadIdx.x;
  if (i < n) p[i] = 0u;
}

// ====================== fused 3-layer systolic LSTM — gll staging + lhp prefetch ======================
// 192 WGs x 512 threads, 1 WG/CU. blockIdx = l*64 + bi*16 + gi.
// WG (l,bi,gi): layer l, batch rows [bi*64,+64), h-cols [gi*32,+32) (=128 gate-cols).
// Wave role kh = wave&1 (0: Whh reads lh; 1: Wih reads lhp), g = wave>>1 (gate).
// SHARED MFMA loop for both roles (R3-proven: keeps the 128-VGPR weight set register-resident;
// R4's split-loop variant spilled wf -> 13.5GB scratch FETCH).
//
// Staging via __builtin_amdgcn_global_load_lds (zero staging VGPRs, async):
//   LDS dest LINEAR row*1024 + lane*16; XOR swizzle applied to the per-lane GLOBAL source
//   offset (lane*16)^((row&7)<<4) — both-sides involution (read side uses swz()).
// Step t schedule:
//   poll fown>=t (quad2: fnext>=t-28) ; issue 8 gll own-h(slot t) ; __syncthreads  [drains
//   own-h AND last step's lhp prefetch] ; shared MFMA ; BAR ; lg writes ; BAR ;
//   ew(__expf) + h stores ; s_waitcnt vmcnt(0) [stores at coherence point] ;
//   poll fprev>=t+2 + issue 8 gll lhp(slot t+2) [prefetch for t+1, in flight across the
//   barrier] ; s_barrier ; tid0 bumps flag.
// Flag/store ordering identical to the proven R2/R3 protocol (stores drained before flag).
// Back-pressure fnext>=t-28: any consumer at step F in [t-28, t-1] has pending reads only on
// prev-slots (F+1),(F+2) != (t+1) except F=t-1 which is flag-ordered. Margin 4 vs D=32.
__global__ __launch_bounds__(512, 2) void k_fused(
    const f16* __restrict__ whh,     // [3][2048][512] fp16
    const f16* __restrict__ wih,     // [3] slabs of G4*HD; layer0 packed [2048][64]
    const float* __restrict__ b0,
    const float* __restrict__ b1,
    const float* __restrict__ b2,
    const f16* __restrict__ xin,     // [512*256][64] fp16
    f16* __restrict__ ring,          // [3][RING_D][256][512] fp16
    int* __restrict__ flags,         // [3][4][16]
    f16* __restrict__ hlast) {       // [256][512] fp16
  const int tid  = threadIdx.x;
  const int lane = tid & 63;
  const int wave = tid >> 6;          // 0..7
  const int l    = blockIdx.x >> 6;   // 0..2
  const int bi   = (blockIdx.x >> 4) & 3;
  const int gi   = blockIdx.x & 15;
  const int ln   = lane & 15;
  const int quad = lane >> 4;
  const int g    = wave >> 1;         // gate 0..3
  const int kh   = wave & 1;          // 0: Whh/lh, 1: Wih/lhp

  __shared__ __align__(16) char smem[131072];
  char*  lh_b  = smem;                 // 64 KiB own h_{t-1} tile (64 rows x 1024B)
  char*  lhp_b = smem + 65536;         // 64 KiB prev h_t tile / x_t tile
  float* lg0   = (float*)smem;         // 32 KiB partial gates (kh=0), aliases lh
  float* lg1   = (float*)(smem + 32768); // 32 KiB partial gates (kh=1), aliases lh

  auto swz = [](int row, int boff) { return row * 1024 + (boff ^ ((row & 7) << 4)); };
  auto lgpos = [](int row, int col) { return row * 128 + (col ^ (((row >> 2) & 7) << 2)); };

  const f16* whh_l = whh + (size_t)l * G4 * HD;
  const f16* wih_l = wih + (size_t)l * G4 * HD;
  const float* bias_l = (l == 0) ? b0 : (l == 1 ? b1 : b2);

  // --- weight fragments -> registers: N=32 x K=512 = 32 frags = 128 VGPR; launder pins ---
  f16x8 wf[16][2];
  if (kh == 0 || l > 0) {
    const f16* W = kh ? wih_l : whh_l;
#pragma unroll
    for (int nb = 0; nb < 2; nb++) {
      const int r = g * 512 + gi * 32 + nb * 16 + ln;   // row in [2048, 512]
#pragma unroll
      for (int ks = 0; ks < 16; ks++) {
        u32x4 tmp = *(const u32x4*)(W + (size_t)r * HD + ks * 32 + quad * 8);
        asm volatile("" : "+v"(tmp));
        wf[ks][nb] = __builtin_bit_cast(f16x8, tmp);
      }
    }
  } else {  // l==0, kh==1: Wih1 is [2048][64]
#pragma unroll
    for (int nb = 0; nb < 2; nb++) {
      const int r = g * 512 + gi * 32 + nb * 16 + ln;
#pragma unroll
      for (int ks = 0; ks < 2; ks++) {
        u32x4 tmp = *(const u32x4*)(wih_l + (size_t)r * NIN + ks * 32 + quad * 8);
        asm volatile("" : "+v"(tmp));
        wf[ks][nb] = __builtin_bit_cast(f16x8, tmp);
      }
    }
  }

  // --- per-thread elementwise state: 4 rows x 1 h-col ---
  const int brow = tid >> 5;
  const int hl_  = tid & 31;
  float cv[4] = {0.f, 0.f, 0.f, 0.f};
  const float bv0 = bias_l[0 * HD + gi * 32 + hl_];
  const float bv1 = bias_l[1 * HD + gi * 32 + hl_];
  const float bv2 = bias_l[2 * HD + gi * 32 + hl_];
  const float bv3 = bias_l[3 * HD + gi * 32 + hl_];

  int* fown = flags + l * 64 + bi * 16;
  int* myflag = fown + gi;
  const int* fprev = (l > 0) ? (flags + (l - 1) * 64 + bi * 16) : fown;
  const int* fnext = (l < 2) ? (flags + (l + 1) * 64 + bi * 16) : fown;

  // ---------------- prologue: lhp <- h^prev_0 (prev ring slot 1) or x_0 ----------------
  if (l > 0) {
    int v = __hip_atomic_load(fprev + ln, __ATOMIC_RELAXED, __HIP_MEMORY_SCOPE_AGENT);
    while (!__all(v >= 1)) {
      __builtin_amdgcn_s_sleep(1);
      v = __hip_atomic_load(fprev + ln, __ATOMIC_RELAXED, __HIP_MEMORY_SCOPE_AGENT);
    }
    asm volatile("" ::: "memory");
    const f16* src = ring + ((size_t)(l - 1) * RING_D + 1) * (BATCH * HD)
                   + (size_t)(bi * BT) * HD;
#pragma unroll
    for (int jj = 0; jj < 8; jj++) {
      const int r = wave * 8 + jj;
      const int gb = (lane * 16) ^ ((r & 7) << 4);
      gll16((const char*)(src + (size_t)r * HD) + gb, lhp_b + r * 1024);
    }
  } else {
    const int xr = tid >> 3, xc = tid & 7;    // 64 rows x 8 chunks of 16B
    u32x4 xv = *(const u32x4*)(xin + ((size_t)(bi * BT + xr)) * NIN + xc * 8);
    *(u32x4*)(lhp_b + swz(xr, xc * 16)) = xv;
  }
  // drained by step-0 BAR1 (__syncthreads)

  for (int t = 0; t < S_LEN; t++) {
    // ---- poll: fown >= t (quad2 carries fnext back-pressure) ----
    {
      const int* fp = fown; int need = t;
      if (quad == 2 && l < 2) { fp = fnext; need = t - 28; }
      int v = __hip_atomic_load(fp + ln, __ATOMIC_RELAXED, __HIP_MEMORY_SCOPE_AGENT);
      while (!__all(v >= need)) {
        __builtin_amdgcn_s_sleep(1);
        v = __hip_atomic_load(fp + ln, __ATOMIC_RELAXED, __HIP_MEMORY_SCOPE_AGENT);
      }
    }
    asm volatile("" ::: "memory");

    // ---- issue own-h staging: 8 async DMAs/wave, zero VGPRs ----
    {
      const f16* src = ring + ((size_t)l * RING_D + (t & (RING_D - 1))) * (BATCH * HD)
                     + (size_t)(bi * BT) * HD;
#pragma unroll
      for (int jj = 0; jj < 8; jj++) {
        const int r = wave * 8 + jj;
        const int gb = (lane * 16) ^ ((r & 7) << 4);
        gll16((const char*)(src + (size_t)r * HD) + gb, lh_b + r * 1024);
      }
    }
    // x(t+1) early-load for l==0 (4 VGPRs live across MFMA; ds_write happens in ew phase)
    u32x4 xv = {};
    if (l == 0 && t + 1 < S_LEN) {
      const int xr = tid >> 3, xc = tid & 7;
      xv = *(const u32x4*)(xin + ((size_t)((t + 1) * 256 + bi * BT + xr)) * NIN + xc * 8);
    }
    __syncthreads();   // BAR1: vmcnt(0)+lgkmcnt(0) -> lh staged, last step's lhp prefetch landed

    // ---- shared MFMA loop: kh0: lh @ Whh^T ; kh1: lhp @ Wih^T  (M=64, N=32) ----
    f32x4 acc[4][2] = {};
    const char* tb = kh ? lhp_b : lh_b;
    const int nks = (kh && l == 0) ? 2 : 16;
    for (int ks = 0; ks < nks; ks++) {
      f16x8 af[4];
#pragma unroll
      for (int mi = 0; mi < 4; mi++)
        af[mi] = *(const f16x8*)(tb + swz(mi * 16 + ln, ks * 64 + quad * 16));
#pragma unroll
      for (int mi = 0; mi < 4; mi++)
#pragma unroll
        for (int nb = 0; nb < 2; nb++)
          acc[mi][nb] = __builtin_amdgcn_mfma_f32_16x16x32_f16(af[mi], wf[ks][nb], acc[mi][nb], 0, 0, 0);
    }
    __syncthreads();   // BAR2: all lh/lhp frag reads done -> lg may overwrite lh

    // ---- write partials (quad-XOR on column kills the 4-way write conflict) ----
    {
      float* lg = kh ? lg1 : lg0;
#pragma unroll
      for (int mi = 0; mi < 4; mi++)
#pragma unroll
        for (int nb = 0; nb < 2; nb++)
#pragma unroll
          for (int rr = 0; rr < 4; rr++) {
            const int row = mi * 16 + quad * 4 + rr;
            const int col = g * 32 + nb * 16 + ln;
            lg[row * 128 + (col ^ (((row >> 2) & 7) << 2))] = acc[mi][nb][rr];
          }
    }
    __syncthreads();   // BAR3: partials visible

    // ---- elementwise LSTM update: 4 (row, h-col) states per thread ----
    f16* hout = ring + ((size_t)l * RING_D + ((t + 1) & (RING_D - 1))) * (BATCH * HD);
#pragma unroll
    for (int s = 0; s < 4; s++) {
      const int row = brow + s * 16;
      const int xm = ((row >> 2) & 7) << 2;
      const int rb = row * 128;
      float g0 = lg0[rb + ((0  + hl_) ^ xm)] + lg1[rb + ((0  + hl_) ^ xm)] + bv0;
      float g1 = lg0[rb + ((32 + hl_) ^ xm)] + lg1[rb + ((32 + hl_) ^ xm)] + bv1;
      float g2 = lg0[rb + ((64 + hl_) ^ xm)] + lg1[rb + ((64 + hl_) ^ xm)] + bv2;
      float g3 = lg0[rb + ((96 + hl_) ^ xm)] + lg1[rb + ((96 + hl_) ^ xm)] + bv3;
      const float igt = 1.f / (1.f + __expf(-g0));
      const float fgt = 1.f / (1.f + __expf(-g1));
      const float ggt = g2 > 0.f ? g2 : (__expf(g2) - 1.f);
      const float ogt = 1.f / (1.f + __expf(-g3));
      cv[s] = fgt * cv[s] + igt * ggt;
      const float hv = ogt * (cv[s] > 0.f ? cv[s] : (__expf(cv[s]) - 1.f));
      f16 hv16 = (f16)hv;
      unsigned short us;
      __builtin_memcpy(&us, &hv16, 2);
      const size_t col = (size_t)(bi * BT + row) * HD + gi * 32 + hl_;
      __hip_atomic_store((unsigned short*)(hout + col), us,
                         __ATOMIC_RELAXED, __HIP_MEMORY_SCOPE_AGENT);
      if (l == 2 && t == S_LEN - 1) hlast[col] = hv16;
    }

    // ---- coherence point for the h stores (PROVEN ordering: stores drained BEFORE the
    //      prefetch is issued, so no counted-vmcnt/store-mixing subtleties) ----
    asm volatile("s_waitcnt vmcnt(0)" ::: "memory");

    // ---- lhp prefetch for step t+1 (in flight across barrier+flag+poll; drained at next BAR1) ----
    if (t + 1 < S_LEN) {
      if (l > 0) {
        int v = __hip_atomic_load(fprev + ln, __ATOMIC_RELAXED, __HIP_MEMORY_SCOPE_AGENT);
        while (!__all(v >= t + 2)) {
          __builtin_amdgcn_s_sleep(1);
          v = __hip_atomic_load(fprev + ln, __ATOMIC_RELAXED, __HIP_MEMORY_SCOPE_AGENT);
        }
        asm volatile("" ::: "memory");
        const f16* src = ring + ((size_t)(l - 1) * RING_D + ((t + 2) & (RING_D - 1))) * (BATCH * HD)
                       + (size_t)(bi * BT) * HD;
#pragma unroll
        for (int jj = 0; jj < 8; jj++) {
          const int r = wave * 8 + jj;
          const int gb = (lane * 16) ^ ((r & 7) << 4);
          gll16((const char*)(src + (size_t)r * HD) + gb, lhp_b + r * 1024);
        }
      } else {
        const int xr = tid >> 3, xc = tid & 7;
        *(u32x4*)(lhp_b + swz(xr, xc * 16)) = xv;   // ds_write; drained at next BAR1
      }
    }

    __builtin_amdgcn_s_barrier();          // BAR4 (raw: prefetch stays in flight)
    __builtin_amdgcn_sched_barrier(0);
    if (tid == 0)
      __hip_atomic_store(myflag, t + 1, __ATOMIC_RELAXED, __HIP_MEMORY_SCOPE_AGENT);
  }
}

// ====================== final FC: y[b] = h_last[b,:] . fc_w + fc_b ======================
__global__ __launch_bounds__(64) void k_fc(const f16* __restrict__ hlast,
                                           const float* __restrict__ fcw,
                                           const float* __restrict__ fcb,
                                           float* __restrict__ out) {
  const int b = blockIdx.x, lane = threadIdx.x;
  const f16* hp = hlast + (size_t)b * HD + lane * 8;
  float s = 0.f;
#pragma unroll
  for (int j = 0; j < 8; j++) s += (float)hp[j] * fcw[lane * 8 + j];
  for (int off = 32; off; off >>= 1) s += __shfl_down(s, off);
  if (lane == 0) out[b] = s + fcb[0];
}

// ============================ host ============================
extern "C" void kernel_launch(void* const* d_in, const int* in_sizes, int n_in,
                              void* d_out, int out_size, void* d_ws, size_t ws_size,
                              hipStream_t stream) {
  (void)in_sizes; (void)n_in; (void)out_size; (void)ws_size;
  const float* x      = (const float*)d_in[0];
  const float* wih[3] = {(const float*)d_in[1], (const float*)d_in[4], (const float*)d_in[7]};
  const float* whh[3] = {(const float*)d_in[2], (const float*)d_in[5], (const float*)d_in[8]};
  const float* bia[3] = {(const float*)d_in[3], (const float*)d_in[6], (const float*)d_in[9]};
  const float* fcw = (const float*)d_in[10];
  const float* fcb = (const float*)d_in[11];
  float* out = (float*)d_out;

  char* ws = (char*)d_ws;
  size_t off = 0;
  auto alloc = [&](size_t bytes) -> char* {
    off = (off + 255) & ~(size_t)255;
    char* p = ws + off;
    off += bytes;
    return p;
  };

  f16* xin   = (f16*)alloc((size_t)S_LEN * BATCH * NIN * 2);
  f16* wih16 = (f16*)alloc((size_t)3 * G4 * HD * 2);
  f16* whh16 = (f16*)alloc((size_t)3 * G4 * HD * 2);
  f16* ring  = (f16*)alloc((size_t)3 * RING_D * BATCH * HD * 2);
  int* flags = (int*)alloc(256 * 4);
  f16* hlast = (f16*)alloc((size_t)BATCH * HD * 2);

  // ---- prep ----
  {
    int n = S_LEN * BATCH * NIN;
    k_x_transpose<<<dim3(n / 256), dim3(256), 0, stream>>>(x, xin);
  }
  k_f32_to_f16<<<dim3((G4 * NIN + 255) / 256), dim3(256), 0, stream>>>(wih[0], wih16, G4 * NIN);
  k_f32_to_f16<<<dim3((G4 * HD + 255) / 256), dim3(256), 0, stream>>>(wih[1], wih16 + (size_t)G4 * HD, G4 * HD);
  k_f32_to_f16<<<dim3((G4 * HD + 255) / 256), dim3(256), 0, stream>>>(wih[2], wih16 + (size_t)2 * G4 * HD, G4 * HD);
  for (int l = 0; l < 3; l++)
    k_f32_to_f16<<<dim3((G4 * HD + 255) / 256), dim3(256), 0, stream>>>(whh[l], whh16 + (size_t)l * G4 * HD, G4 * HD);
  // zero ring slot 0 of each layer (h_{-1}=0) + flags
  for (int l = 0; l < 3; l++)
    k_zero_i32<<<dim3(BATCH * HD / 2 / 256), dim3(256), 0, stream>>>(
        (uint32_t*)(ring + (size_t)l * RING_D * BATCH * HD), BATCH * HD / 2);
  k_zero_i32<<<dim3(1), dim3(256), 0, stream>>>((uint32_t*)flags, 192);

  // ---- single fused systolic launch (192 WGs, 1/CU, gll staging + lhp prefetch) ----
  k_fused<<<dim3(192), dim3(512), 0, stream>>>(whh16, wih16, bia[0], bia[1], bia[2],
                                               xin, ring, flags, hlast);

  // ---- final FC ----
  k_fc<<<dim3(BATCH), dim3(64), 0, stream>>>(hlast, fcw, fcb, out);
}

// Round 6
// 7043.376 us; speedup vs baseline: 1.4020x; 1.0962x over previous
//
#include <hip/hip_runtime.h>
#include <stdint.h>
#include <stddef.h>

#define S_LEN 512
#define BATCH 256
#define NIN   64
#define HD    512
#define G4    2048   // 4*H
#define RING_D 8     // ring depth (pow2); back-pressure enforced at t-6 (bound t-7)
#define BT    64     // batch rows per WG

typedef _Float16 f16;
typedef _Float16 f16x8 __attribute__((ext_vector_type(8)));
typedef float    f32x4 __attribute__((ext_vector_type(4)));
typedef uint32_t u32x4 __attribute__((ext_vector_type(4)));
typedef uint64_t u64x2 __attribute__((ext_vector_type(2)));

typedef __attribute__((address_space(3))) void lds_as;
typedef const __attribute__((address_space(1))) void glb_as;

// async global->LDS, 16B/lane, aux=1 = SC0 only: bypass L1, serve from the XCD-local L2.
// (R5 ERRATA: aux=17 = SC0|SC1 = SYSTEM scope -> bypassed L2 AND MALL -> 13GB HBM FETCH.)
static __device__ __forceinline__ void gll16_l2(const void* g, void* l) {
  __builtin_amdgcn_global_load_lds((glb_as*)g, (lds_as*)l, 16, 0, 1);
}

// ============================ prep kernels ============================
__global__ void k_f32_to_f16(const float* __restrict__ src, f16* __restrict__ dst, int n) {
  int i = blockIdx.x * 256 + threadIdx.x;
  if (i < n) dst[i] = (f16)src[i];
}

// x [B,S,I] fp32 -> xin [(s*256+b)*64+i] fp16
__global__ void k_x_transpose(const float* __restrict__ x, f16* __restrict__ xin) {
  int idx = blockIdx.x * 256 + threadIdx.x;
  int i  = idx & 63;
  int sb = idx >> 6;
  int b  = sb & 255;
  int s  = sb >> 8;
  xin[idx] = (f16)x[((size_t)b * S_LEN + s) * NIN + i];
}

__global__ void k_zero_i32(uint32_t* p, int n) {
  int i = blockIdx.x * 256 + threadIdx.x;
  if (i < n) p[i] = 0u;
}

// ====================== fused 3-layer systolic LSTM — XCD-local h exchange ======================
// Grid 256 WGs x 512 thr (64 dummies exit). xcd=blockIdx&7, slot=blockIdx>>3 (HW round-robin):
//   xcd<4 : slot<16 -> (l=0, bi=xcd, gi=slot) ; slot>=16 -> (l=1, bi=xcd, gi=slot-16)
//   xcd>=4: slot<16 -> (l=2, bi=xcd-4, gi=slot) ; else DUMMY
// So group (l,bi) = 16 gi-WGs shares one XCD, and (l0,bi)+(l1,bi) PAIR shares one XCD.
// h exchange (the R3 bottleneck: 24.6 MB/step broadcast through MALL at ~2.2 TB/s = 11.5us/step):
//   - producers DUAL-STORE h: plain store -> ringL (stays in XCD L2) + agent atomic -> ringM (MALL).
//   - lh (own group) and l1's lhp (l0 same XCD): gll16_l2 from ringL -> L2-served (4.3 TB/s/XCD).
//   - l2's lhp: R3-proven agent-atomic path from ringM (only 4 MB/step through MALL).
// Placement is VERIFIED at runtime: every WG publishes s_getreg(HW_REG_XCC_ID) to xcdmap; a
// consumer uses the L2 path ONLY if all its producers published the same XCD. Wrong placement
// -> graceful fallback to the MALL path (R3 perf floor), never wrongness/deadlock.
// Everything else (kh wave-split shared MFMA loop, lg partials, ew, 4 barriers, monotone flags,
// store->vmcnt-drain->flag order) is R3 verbatim. RING_D=8: fnext>=t-6 (provable bound t-7);
// own-group is in exact lockstep (poll needs all fown>=t), so lh slot reuse distance is 8 safely.
__global__ __launch_bounds__(512, 2) void k_fused(
    const f16* __restrict__ whh,     // [3][2048][512] fp16
    const f16* __restrict__ wih,     // [3] slabs of G4*HD; layer0 packed [2048][64]
    const float* __restrict__ b0,
    const float* __restrict__ b1,
    const float* __restrict__ b2,
    const f16* __restrict__ xin,     // [512*256][64] fp16
    f16* __restrict__ ringM,         // [3][RING_D][256][512] fp16  (MALL ring, agent atomics)
    f16* __restrict__ ringL,         // [3][RING_D][256][512] fp16  (L2 ring, plain st / sc0 ld)
    int* __restrict__ flags,         // [3][4][16]
    int* __restrict__ xcdmap,        // [256] published XCC_ID+1
    f16* __restrict__ hlast) {       // [256][512] fp16
  const int tid  = threadIdx.x;
  const int lane = tid & 63;
  const int wave = tid >> 6;          // 0..7
  const int xcd  = blockIdx.x & 7;
  const int slot = blockIdx.x >> 3;   // 0..31
  int l, bi, gi;
  if (xcd < 4) { bi = xcd; l = slot >> 4; gi = slot & 15; }
  else         { if (slot >= 16) return; l = 2; bi = xcd - 4; gi = slot; }
  const int ln   = lane & 15;
  const int quad = lane >> 4;
  const int g    = wave >> 1;         // gate 0..3
  const int kh   = wave & 1;          // 0: Whh/lh, 1: Wih/lhp

  __shared__ __align__(16) char smem[131072];
  char*  lh_b  = smem;                 // 64 KiB own h_{t-1} tile (64 rows x 1024B)
  char*  lhp_b = smem + 65536;         // 64 KiB prev h_t tile / x_t tile
  float* lg0   = (float*)smem;         // 32 KiB partial gates (kh=0), aliases lh
  float* lg1   = (float*)(smem + 32768); // 32 KiB partial gates (kh=1), aliases lh

  auto swz = [](int row, int boff) { return row * 1024 + (boff ^ ((row & 7) << 4)); };
  auto bid_of = [](int ll, int bb, int gg) {
    return (ll == 2) ? ((gg << 3) | (bb + 4)) : ((((ll << 4) + gg) << 3) | bb);
  };

  const f16* whh_l = whh + (size_t)l * G4 * HD;
  const f16* wih_l = wih + (size_t)l * G4 * HD;
  const float* bias_l = (l == 0) ? b0 : (l == 1 ? b1 : b2);

  // --- publish my actual XCD; derive exchange paths (fallback-safe) ---
  unsigned myxcc;
  asm volatile("s_getreg_b32 %0, hwreg(HW_REG_XCC_ID)" : "=s"(myxcc));
  if (tid == 0)
    __hip_atomic_store(xcdmap + blockIdx.x, (int)myxcc + 1, __ATOMIC_RELAXED, __HIP_MEMORY_SCOPE_AGENT);
  bool lh_local = false, lhp_local = false;
  {
    const int mb = bid_of(l, bi, ln);
    int v = __hip_atomic_load(xcdmap + mb, __ATOMIC_RELAXED, __HIP_MEMORY_SCOPE_AGENT);
    while (!__all(v > 0)) {
      __builtin_amdgcn_s_sleep(2);
      v = __hip_atomic_load(xcdmap + mb, __ATOMIC_RELAXED, __HIP_MEMORY_SCOPE_AGENT);
    }
    lh_local = __all(v == (int)myxcc + 1);
  }
  if (l == 1) {
    const int pb = bid_of(0, bi, ln);
    int v = __hip_atomic_load(xcdmap + pb, __ATOMIC_RELAXED, __HIP_MEMORY_SCOPE_AGENT);
    while (!__all(v > 0)) {
      __builtin_amdgcn_s_sleep(2);
      v = __hip_atomic_load(xcdmap + pb, __ATOMIC_RELAXED, __HIP_MEMORY_SCOPE_AGENT);
    }
    lhp_local = __all(v == (int)myxcc + 1);
  }

  // --- weight fragments -> registers (kh0: Whh; kh1: Wih); launder pins (R3-proven: land in
  //     the AGPR half, VGPR_Count~128, no scratch) ---
  f16x8 wf[16][2];
  if (kh == 0 || l > 0) {
    const f16* W = kh ? wih_l : whh_l;
#pragma unroll
    for (int nb = 0; nb < 2; nb++) {
      const int r = g * 512 + gi * 32 + nb * 16 + ln;
#pragma unroll
      for (int ks = 0; ks < 16; ks++) {
        u32x4 tmp = *(const u32x4*)(W + (size_t)r * HD + ks * 32 + quad * 8);
        asm volatile("" : "+v"(tmp));
        wf[ks][nb] = __builtin_bit_cast(f16x8, tmp);
      }
    }
  } else {  // l==0, kh==1: Wih1 is [2048][64]
#pragma unroll
    for (int nb = 0; nb < 2; nb++) {
      const int r = g * 512 + gi * 32 + nb * 16 + ln;
#pragma unroll
      for (int ks = 0; ks < 2; ks++) {
        u32x4 tmp = *(const u32x4*)(wih_l + (size_t)r * NIN + ks * 32 + quad * 8);
        asm volatile("" : "+v"(tmp));
        wf[ks][nb] = __builtin_bit_cast(f16x8, tmp);
      }
    }
  }

  // --- per-thread elementwise state: 4 rows x 1 h-col ---
  const int brow = tid >> 5;
  const int hl_  = tid & 31;
  float cv[4] = {0.f, 0.f, 0.f, 0.f};
  const float bv0 = bias_l[0 * HD + gi * 32 + hl_];
  const float bv1 = bias_l[1 * HD + gi * 32 + hl_];
  const float bv2 = bias_l[2 * HD + gi * 32 + hl_];
  const float bv3 = bias_l[3 * HD + gi * 32 + hl_];

  int* fown = flags + l * 64 + bi * 16;
  int* myflag = fown + gi;
  const int* fprev = (l > 0) ? (flags + (l - 1) * 64 + bi * 16) : fown;
  const int* fnext = (l < 2) ? (flags + (l + 1) * 64 + bi * 16) : fown;

  for (int t = 0; t < S_LEN; t++) {
    // ---- all waves poll (quad roles, R3 verbatim; D=8 -> fnext >= t-6) ----
    {
      const int* fp = fown;
      int need = t;
      if (quad == 1 && l > 0)      { fp = fprev; need = t + 1; }
      else if (quad == 2 && l < 2) { fp = fnext; need = t + 2 - RING_D; }
      int v = __hip_atomic_load(fp + ln, __ATOMIC_RELAXED, __HIP_MEMORY_SCOPE_AGENT);
      while (!__all(v >= need)) {
        __builtin_amdgcn_s_sleep(1);
        v = __hip_atomic_load(fp + ln, __ATOMIC_RELAXED, __HIP_MEMORY_SCOPE_AGENT);
      }
    }
    asm volatile("" ::: "memory");   // keep data loads below the poll

    // ---- stage own h_{t-1} (slot t%D) -> lh ----
    if (lh_local) {
      const f16* src = ringL + ((size_t)l * RING_D + (t & (RING_D - 1))) * (BATCH * HD)
                     + (size_t)(bi * BT) * HD;
#pragma unroll
      for (int jj = 0; jj < 8; jj++) {
        const int r = wave * 8 + jj;
        const int gb = (lane * 16) ^ ((r & 7) << 4);   // source-side swizzle, LDS dest linear
        gll16_l2((const char*)(src + (size_t)r * HD) + gb, lh_b + r * 1024);
      }
    } else {
      const uint64_t* hown = (const uint64_t*)(ringM
          + ((size_t)l * RING_D + (t & (RING_D - 1))) * (BATCH * HD)
          + (size_t)(bi * BT) * HD);
      uint64_t a0[8], a1[8];
#pragma unroll
      for (int j = 0; j < 8; j++) {
        a0[j] = __hip_atomic_load(hown + j * 1024 + tid * 2,     __ATOMIC_RELAXED, __HIP_MEMORY_SCOPE_AGENT);
        a1[j] = __hip_atomic_load(hown + j * 1024 + tid * 2 + 1, __ATOMIC_RELAXED, __HIP_MEMORY_SCOPE_AGENT);
      }
#pragma unroll
      for (int j = 0; j < 8; j++) {
        const int e = j * 1024 + tid * 2, row = e >> 7, c8 = e & 127;
        u64x2 p; p[0] = a0[j]; p[1] = a1[j];
        *(u64x2*)(lh_b + swz(row, c8 * 8)) = p;
      }
    }

    // ---- stage prev h_t (slot (t+1)%D) / x_t -> lhp ----
    if (l == 0) {
      const int xr = tid >> 3, xc = tid & 7;   // 64 rows x 8 chunks of 16B
      u32x4 xv = *(const u32x4*)(xin + ((size_t)(t * 256 + bi * BT + xr)) * NIN + xc * 8);
      *(u32x4*)(lhp_b + swz(xr, xc * 16)) = xv;
    } else if (l == 1 && lhp_local) {
      const f16* src = ringL + ((size_t)0 * RING_D + ((t + 1) & (RING_D - 1))) * (BATCH * HD)
                     + (size_t)(bi * BT) * HD;
#pragma unroll
      for (int jj = 0; jj < 8; jj++) {
        const int r = wave * 8 + jj;
        const int gb = (lane * 16) ^ ((r & 7) << 4);
        gll16_l2((const char*)(src + (size_t)r * HD) + gb, lhp_b + r * 1024);
      }
    } else {
      const uint64_t* hprev = (const uint64_t*)(ringM
          + ((size_t)(l - 1) * RING_D + ((t + 1) & (RING_D - 1))) * (BATCH * HD)
          + (size_t)(bi * BT) * HD);
      uint64_t p0[8], p1[8];
#pragma unroll
      for (int j = 0; j < 8; j++) {
        p0[j] = __hip_atomic_load(hprev + j * 1024 + tid * 2,     __ATOMIC_RELAXED, __HIP_MEMORY_SCOPE_AGENT);
        p1[j] = __hip_atomic_load(hprev + j * 1024 + tid * 2 + 1, __ATOMIC_RELAXED, __HIP_MEMORY_SCOPE_AGENT);
      }
#pragma unroll
      for (int j = 0; j < 8; j++) {
        const int e = j * 1024 + tid * 2, row = e >> 7, c8 = e & 127;
        u64x2 p; p[0] = p0[j]; p[1] = p1[j];
        *(u64x2*)(lhp_b + swz(row, c8 * 8)) = p;
      }
    }
    __syncthreads();   // BAR1: vmcnt+lgkm drained -> both tiles staged

    // ---- shared MFMA loop (R3-proven): kh0: lh @ Whh^T ; kh1: lhp @ Wih^T  (M=64,N=32) ----
    f32x4 acc[4][2] = {};
    const char* tb = kh ? lhp_b : lh_b;
    const int nks = (kh && l == 0) ? 2 : 16;
    for (int ks = 0; ks < nks; ks++) {
      f16x8 af[4];
#pragma unroll
      for (int mi = 0; mi < 4; mi++)
        af[mi] = *(const f16x8*)(tb + swz(mi * 16 + ln, ks * 64 + quad * 16));
#pragma unroll
      for (int mi = 0; mi < 4; mi++)
#pragma unroll
        for (int nb = 0; nb < 2; nb++)
          acc[mi][nb] = __builtin_amdgcn_mfma_f32_16x16x32_f16(af[mi], wf[ks][nb], acc[mi][nb], 0, 0, 0);
    }
    __syncthreads();   // BAR2: all frag reads done -> lg may overwrite lh

    // ---- write partials (quad-XOR column swizzle kills the 4-way write conflict) ----
    {
      float* lg = kh ? lg1 : lg0;
#pragma unroll
      for (int mi = 0; mi < 4; mi++)
#pragma unroll
        for (int nb = 0; nb < 2; nb++)
#pragma unroll
          for (int rr = 0; rr < 4; rr++) {
            const int row = mi * 16 + quad * 4 + rr;
            const int col = g * 32 + nb * 16 + ln;
            lg[row * 128 + (col ^ (((row >> 2) & 7) << 2))] = acc[mi][nb][rr];
          }
    }
    __syncthreads();   // BAR3: partials visible

    // ---- elementwise LSTM update: 4 (row, h-col) states; DUAL-STORE h ----
    const size_t slotoff = ((size_t)l * RING_D + ((t + 1) & (RING_D - 1))) * (BATCH * HD);
    f16* houtM = ringM + slotoff;
    f16* houtL = ringL + slotoff;
#pragma unroll
    for (int s = 0; s < 4; s++) {
      const int row = brow + s * 16;
      const int xm = ((row >> 2) & 7) << 2;
      const int rb = row * 128;
      float g0 = lg0[rb + ((0  + hl_) ^ xm)] + lg1[rb + ((0  + hl_) ^ xm)] + bv0;
      float g1 = lg0[rb + ((32 + hl_) ^ xm)] + lg1[rb + ((32 + hl_) ^ xm)] + bv1;
      float g2 = lg0[rb + ((64 + hl_) ^ xm)] + lg1[rb + ((64 + hl_) ^ xm)] + bv2;
      float g3 = lg0[rb + ((96 + hl_) ^ xm)] + lg1[rb + ((96 + hl_) ^ xm)] + bv3;
      const float igt = 1.f / (1.f + __expf(-g0));
      const float fgt = 1.f / (1.f + __expf(-g1));
      const float ggt = g2 > 0.f ? g2 : (__expf(g2) - 1.f);
      const float ogt = 1.f / (1.f + __expf(-g3));
      cv[s] = fgt * cv[s] + igt * ggt;
      const float hv = ogt * (cv[s] > 0.f ? cv[s] : (__expf(cv[s]) - 1.f));
      f16 hv16 = (f16)hv;
      unsigned short us;
      __builtin_memcpy(&us, &hv16, 2);
      const size_t col = (size_t)(bi * BT + row) * HD + gi * 32 + hl_;
      houtL[col] = hv16;   // plain -> XCD L2 (local consumers)
      __hip_atomic_store((unsigned short*)(houtM + col), us,
                         __ATOMIC_RELAXED, __HIP_MEMORY_SCOPE_AGENT);  // MALL (remote consumers)
      if (l == 2 && t == S_LEN - 1) hlast[col] = hv16;
    }
    __syncthreads();   // BAR4: drains every wave's vmcnt -> BOTH store sets at coherence points
    if (tid == 0)
      __hip_atomic_store(myflag, t + 1, __ATOMIC_RELAXED, __HIP_MEMORY_SCOPE_AGENT);
  }
}

// ====================== final FC: y[b] = h_last[b,:] . fc_w + fc_b ======================
__global__ __launch_bounds__(64) void k_fc(const f16* __restrict__ hlast,
                                           const float* __restrict__ fcw,
                                           const float* __restrict__ fcb,
                                           float* __restrict__ out) {
  const int b = blockIdx.x, lane = threadIdx.x;
  const f16* hp = hlast + (size_t)b * HD + lane * 8;
  float s = 0.f;
#pragma unroll
  for (int j = 0; j < 8; j++) s += (float)hp[j] * fcw[lane * 8 + j];
  for (int off = 32; off; off >>= 1) s += __shfl_down(s, off);
  if (lane == 0) out[b] = s + fcb[0];
}

// ============================ host ============================
extern "C" void kernel_launch(void* const* d_in, const int* in_sizes, int n_in,
                              void* d_out, int out_size, void* d_ws, size_t ws_size,
                              hipStream_t stream) {
  (void)in_sizes; (void)n_in; (void)out_size; (void)ws_size;
  const float* x      = (const float*)d_in[0];
  const float* wih[3] = {(const float*)d_in[1], (const float*)d_in[4], (const float*)d_in[7]};
  const float* whh[3] = {(const float*)d_in[2], (const float*)d_in[5], (const float*)d_in[8]};
  const float* bia[3] = {(const float*)d_in[3], (const float*)d_in[6], (const float*)d_in[9]};
  const float* fcw = (const float*)d_in[10];
  const float* fcb = (const float*)d_in[11];
  float* out = (float*)d_out;

  char* ws = (char*)d_ws;
  size_t off = 0;
  auto alloc = [&](size_t bytes) -> char* {
    off = (off + 255) & ~(size_t)255;
    char* p = ws + off;
    off += bytes;
    return p;
  };

  f16* xin   = (f16*)alloc((size_t)S_LEN * BATCH * NIN * 2);
  f16* wih16 = (f16*)alloc((size_t)3 * G4 * HD * 2);
  f16* whh16 = (f16*)alloc((size_t)3 * G4 * HD * 2);
  f16* ringM = (f16*)alloc((size_t)3 * RING_D * BATCH * HD * 2);
  f16* ringL = (f16*)alloc((size_t)3 * RING_D * BATCH * HD * 2);
  int* flags = (int*)alloc(256 * 4);
  int* xcdmap= (int*)alloc(256 * 4);
  f16* hlast = (f16*)alloc((size_t)BATCH * HD * 2);

  // ---- prep ----
  {
    int n = S_LEN * BATCH * NIN;
    k_x_transpose<<<dim3(n / 256), dim3(256), 0, stream>>>(x, xin);
  }
  k_f32_to_f16<<<dim3((G4 * NIN + 255) / 256), dim3(256), 0, stream>>>(wih[0], wih16, G4 * NIN);
  k_f32_to_f16<<<dim3((G4 * HD + 255) / 256), dim3(256), 0, stream>>>(wih[1], wih16 + (size_t)G4 * HD, G4 * HD);
  k_f32_to_f16<<<dim3((G4 * HD + 255) / 256), dim3(256), 0, stream>>>(wih[2], wih16 + (size_t)2 * G4 * HD, G4 * HD);
  for (int l = 0; l < 3; l++)
    k_f32_to_f16<<<dim3((G4 * HD + 255) / 256), dim3(256), 0, stream>>>(whh[l], whh16 + (size_t)l * G4 * HD, G4 * HD);
  // zero ring slot 0 of each layer, BOTH rings (h_{-1}=0) + flags + xcdmap
  for (int l = 0; l < 3; l++) {
    k_zero_i32<<<dim3(BATCH * HD / 2 / 256), dim3(256), 0, stream>>>(
        (uint32_t*)(ringM + (size_t)l * RING_D * BATCH * HD), BATCH * HD / 2);
    k_zero_i32<<<dim3(BATCH * HD / 2 / 256), dim3(256), 0, stream>>>(
        (uint32_t*)(ringL + (size_t)l * RING_D * BATCH * HD), BATCH * HD / 2);
  }
  k_zero_i32<<<dim3(1), dim3(256), 0, stream>>>((uint32_t*)flags, 192);
  k_zero_i32<<<dim3(1), dim3(256), 0, stream>>>((uint32_t*)xcdmap, 256);

  // ---- single fused systolic launch: 256 WGs (64 dummies), XCD-colocated groups ----
  k_fused<<<dim3(256), dim3(512), 0, stream>>>(whh16, wih16, bia[0], bia[1], bia[2],
                                               xin, ringM, ringL, flags, xcdmap, hlast);

  // ---- final FC ----
  k_fc<<<dim3(BATCH), dim3(64), 0, stream>>>(hlast, fcw, fcb, out);
}